// Round 2
// baseline (7159.581 us; speedup 1.0000x reference)
//
#include <hip/hip_runtime.h>
#include <cmath>

typedef __attribute__((ext_vector_type(8))) short short8;
typedef __attribute__((ext_vector_type(4))) float f32x4;
typedef unsigned long long u64;
typedef unsigned int u32;

#define RS 2208             // safe-kernel A row stride in bf16
#define TICKS_MS 100000ull  // s_memrealtime ~100 MHz -> 1 ms
#define SCAN_SPIN (1u << 18)

__device__ __forceinline__ unsigned short f2bf(float x){
  u32 u = __float_as_uint(x);
  u32 r = u + 0x7FFFu + ((u >> 16) & 1u);   // round-to-nearest-even bf16
  return (unsigned short)(r >> 16);
}

__device__ __forceinline__ float tanh_fast(float x){
  float xc = fminf(fmaxf(x, -10.f), 10.f);
  float e = __expf(2.f * xc);
  return (e - 1.f) / (e + 1.f);
}

__device__ __forceinline__ u64 rtc(){ return __builtin_amdgcn_s_memrealtime(); }

// SE-scope (sc0) ops: bypass L1, served by the XCD-shared L2. Used only after
// the bounded pre-flight proves the 32-block ring sees each other's sc0 stores
// as VALUE CHANGES (lockstep ping-pong), i.e. same-XCD + fresh loads.
__device__ __forceinline__ u64 ld_sc0(const u64* p){
  u64 v;
  asm volatile("global_load_dwordx2 %0, %1, off sc0\n\ts_waitcnt vmcnt(0)"
               : "=v"(v) : "v"(p) : "memory");
  return v;
}
__device__ __forceinline__ void st_sc0(u64* p, u64 v){
  asm volatile("global_store_dwordx2 %0, %1, off sc0" :: "v"(p), "v"(v) : "memory");
}
__device__ __forceinline__ void ld2_sc0(const u64* p0, const u64* p1, u64& a, u64& b){
  asm volatile("global_load_dwordx2 %0, %2, off sc0\n\t"
               "global_load_dwordx2 %1, %3, off sc0\n\t"
               "s_waitcnt vmcnt(0)"
               : "=&v"(a), "=&v"(b) : "v"(p0), "v"(p1) : "memory");
}

// Pre-swizzle [w_res ; w_in] (K=2176 x 2048 cols) into bf16 MFMA B-fragment order.
// short8 index = ((gcg*68 + fu)*64 + l); k = fu*32 + (l>>4)*8 + j, col = gcg*16 + (l&15).
// Same bytes serve both kernels (safe kernel addresses it as (gcg*2+ks)*34+f).
__global__ void bswz_kernel(const float* __restrict__ wres,
                            const float* __restrict__ win,
                            unsigned short* __restrict__ B){
  int tid = blockIdx.x * 256 + threadIdx.x;
  int l   = tid & 63;
  int cf  = tid >> 6;
  int f   = cf % 34;
  int gk  = cf / 34;
  int ks  = gk & 1;
  int gcg = gk >> 1;
  int col = (gcg << 4) + (l & 15);
  int k0  = ks * 1088 + (f << 5) + ((l >> 4) << 3);
  short8 vv;
  #pragma unroll
  for (int j = 0; j < 8; ++j){
    int k = k0 + j;
    float v = (k < 2048) ? wres[(size_t)k * 2048 + col]
                         : win[(size_t)(k - 2048) * 2048 + col];
    vv[j] = (short)f2bf(v);
  }
  *((short8*)(B + (size_t)tid * 8)) = vv;
}

// out[b][t][0:128] = inputs  (concat head).
__global__ void copy_in_kernel(const float* __restrict__ in, float* __restrict__ out){
  int i = blockIdx.x * 256 + threadIdx.x;
  int bt = i >> 5;
  int d4 = i & 31;
  float4 v = ((const float4*)in)[i];
  ((float4*)(out + (size_t)bt * 2176))[d4] = v;
}

// ex[2][8][512] u64 (parity 0 = tag 0, valid s_0=0 for t=0; parity 1 = tag 1),
// then ctrl u32[16] (cnt, okcnt, verdict) + tslots[256] u64, all zeroed.
__global__ void exinit_kernel(u64* __restrict__ ex){
  int i = blockIdx.x * 256 + threadIdx.x;   // 8704 entries
  if (i < 8192)      ex[i] = (i < 4096) ? 0ULL : 0x0001000100010001ULL;
  else if (i < 8704) ex[i] = 0ULL;
}

// ---------------- WIDE: 256 blocks x 256 threads, 1 block/CU ----------------
// Block blk: row r = blk&7, cols [cb*64, cb*64+64), cb = blk>>3.  With the
// observed blockIdx%8 -> XCD round-robin, each row's 32-block exchange ring is
// XCD-local; the bounded lockstep ping-pong VERIFIES that (and sc0 freshness)
// before committing. Verdict!=1 -> exit untouched; esn_safe then runs.
__global__ void __launch_bounds__(256, 1) esn_wide(
    const float* __restrict__ inputs,
    const float* __restrict__ b_in,
    const unsigned short* __restrict__ Bsw,
    u64* __restrict__ ex,
    float* __restrict__ out)
{
  __shared__ __align__(16) unsigned short As[2][2176]; // [parity][2048 state + 128 x_t]
  __shared__ int sflag;

  const int tid = threadIdx.x;
  const int blk = blockIdx.x;      // 0..255
  const int r   = blk & 7;
  const int cb  = blk >> 3;        // 0..31
  u32* ctrl   = (u32*)(ex + 8192);           // [0]=cnt [1]=okcnt [2]=verdict
  u64* tslots = ex + 8192 + 8;

  // ---- clock-bounded pre-flight (tid 0 only; deadlock-free by construction) ----
  if (tid == 0){
    __hip_atomic_fetch_add(&ctrl[0], 1u, __ATOMIC_RELAXED, __HIP_MEMORY_SCOPE_AGENT);
    const int partner = (((cb + 1) & 31) << 3) | r;   // ring within the row group
    int ok = 1;
    for (int rd = 1; rd <= 4 && ok; ++rd){            // lockstep: each round needs a FRESH value
      st_sc0(&tslots[blk], (u64)rd);
      u64 tend = rtc() + TICKS_MS;
      u64 v;
      do { v = ld_sc0(&tslots[partner]); } while (v < (u64)rd && rtc() < tend);
      ok = (v >= (u64)rd) ? 1 : 0;
    }
    if (ok) __hip_atomic_fetch_add(&ctrl[1], 1u, __ATOMIC_RELAXED, __HIP_MEMORY_SCOPE_AGENT);
    if (blk == 0){
      u64 tend = rtc() + 3 * TICKS_MS;
      u32 c, o;
      do {
        c = __hip_atomic_load(&ctrl[0], __ATOMIC_RELAXED, __HIP_MEMORY_SCOPE_AGENT);
        o = __hip_atomic_load(&ctrl[1], __ATOMIC_RELAXED, __HIP_MEMORY_SCOPE_AGENT);
      } while (!(c == 256u && o == 256u) && rtc() < tend);
      __hip_atomic_store(&ctrl[2], (c == 256u && o == 256u) ? 1u : 2u,
                         __ATOMIC_RELAXED, __HIP_MEMORY_SCOPE_AGENT);
    }
    u64 tend = rtc() + 12 * TICKS_MS;
    u32 v;
    do { v = __hip_atomic_load(&ctrl[2], __ATOMIC_RELAXED, __HIP_MEMORY_SCOPE_AGENT); }
    while (v == 0u && rtc() < tend);
    sflag = (v == 1u);
  }
  __syncthreads();
  if (!sflag) return;

  // ---- committed: load B fragments (full K=2176: 68 short8 = 272 VGPR) ----
  const int w   = tid >> 6;        // wave 0..3 = col-group
  const int l   = tid & 63;
  const int m16 = l & 15;
  const int q   = l >> 4;
  const int gcg = (cb << 2) + w;   // 0..127
  const int colw0 = gcg << 4;

  short8 Bf[68];
  {
    const short8* bp = (const short8*)Bsw + (size_t)gcg * (68 * 64) + l;
    #pragma unroll
    for (int f = 0; f < 68; ++f) Bf[f] = bp[f * 64];
  }
  const float bias = b_in[colw0 + m16];
  float s = 0.f;
  const float* xr = inputs + (size_t)r * 1024 * 128;
  const u64 M = 0x0001000100010001ULL;

  float4 xv;
  if (tid < 32) xv = ((const float4*)xr)[tid];      // prefetch x_0

  for (int t = 0; t < 1024; ++t){
    const int p = t & 1;
    unsigned short* Ap = &As[p][0];

    // stage x_t from regs; issue prefetch of x_{t+1} (overlaps the poll)
    if (tid < 32){
      u64 pk = (u64)f2bf(xv.x) | ((u64)f2bf(xv.y) << 16)
             | ((u64)f2bf(xv.z) << 32) | ((u64)f2bf(xv.w) << 48);
      *((u64*)&Ap[2048 + (tid << 2)]) = pk;
      if (t < 1023) xv = ((const float4*)(xr + (size_t)(t + 1) * 128))[tid];
    }
    // poll 2 tagged entries/thread (row r, 512 entries) via sc0 from XCD L2
    {
      u64* srcb = ex + ((size_t)p * 8 + r) * 512;
      const u64 want = ((t >> 1) & 1) ? M : 0ULL;
      u64 v0, v1;
      ld2_sc0(&srcb[tid], &srcb[tid + 256], v0, v1);
      u32 pend = 3, guard = 0;
      while (pend){
        u32 np = 0;
        if (pend & 1){ if ((v0 & M) == want) *((u64*)&Ap[tid << 2]) = v0; else np |= 1; }
        if (pend & 2){ if ((v1 & M) == want) *((u64*)&Ap[(tid + 256) << 2]) = v1; else np |= 2; }
        pend = np;
        if (pend){
          if (++guard > SCAN_SPIN){   // liveness guard: terminate, never hang
            if (pend & 1) *((u64*)&Ap[tid << 2]) = v0;
            if (pend & 2) *((u64*)&Ap[(tid + 256) << 2]) = v1;
            break;
          }
          if (pend & 1) v0 = ld_sc0(&srcb[tid]);
          if (pend & 2) v1 = ld_sc0(&srcb[tid + 256]);
        }
      }
    }
    __syncthreads();   // single barrier/step; As parity-double-buffered

    // MFMA: full K=2176, 68 x 16x16x32, 4 interleaved acc chains, M=1 broadcast
    f32x4 a0 = {0,0,0,0}, a1 = {0,0,0,0}, a2 = {0,0,0,0}, a3 = {0,0,0,0};
    {
      const unsigned short* Ab = Ap + (q << 3);
      #pragma unroll
      for (int f = 0; f < 68; f += 4){
        short8 x0 = *((const short8*)(Ab + ((f + 0) << 5)));
        short8 x1 = *((const short8*)(Ab + ((f + 1) << 5)));
        short8 x2 = *((const short8*)(Ab + ((f + 2) << 5)));
        short8 x3 = *((const short8*)(Ab + ((f + 3) << 5)));
        a0 = __builtin_amdgcn_mfma_f32_16x16x32_bf16(x0, Bf[f + 0], a0, 0, 0, 0);
        a1 = __builtin_amdgcn_mfma_f32_16x16x32_bf16(x1, Bf[f + 1], a1, 0, 0, 0);
        a2 = __builtin_amdgcn_mfma_f32_16x16x32_bf16(x2, Bf[f + 2], a2, 0, 0, 0);
        a3 = __builtin_amdgcn_mfma_f32_16x16x32_bf16(x3, Bf[f + 3], a3, 0, 0, 0);
      }
    }
    if (l < 16){
      float pre = ((a0[0] + a1[0]) + (a2[0] + a3[0])) + bias;
      float nv = 0.5f * s + 0.5f * tanh_fast(pre);
      s = nv;
      const u32 bit = (u32)(((t + 1) >> 1) & 1);
      u32 b0 = ((u32)f2bf(nv) & 0xFFFEu) | bit;        // tag-bit in bf16 LSB
      u32 pr = b0 | (((u32)__shfl_xor((int)b0, 1)) << 16);
      u64 e  = (u64)pr | ((u64)(u32)__shfl_xor((int)pr, 2) << 32);
      if ((m16 & 3) == 0){
        u64* exw = ex + ((size_t)((t + 1) & 1) * 8 + r) * 512;
        st_sc0(&exw[(colw0 + m16) >> 2], e);           // publish first
      }
      const int u = colw0 + m16;
      float pw = (u & 1) ? nv : nv * nv;               // PowerIndex: even u squared
      out[((size_t)r * 1024 + t) * 2176 + 128 + u] = pw;
    }
  }
}

// ---------------- SAFE: verbatim proven 3.08ms kernel, verdict-gated ----------------
__global__ void __launch_bounds__(512, 2) esn_safe(
    const float* __restrict__ inputs,
    const float* __restrict__ b_in,
    const unsigned short* __restrict__ Bsw,
    u64* __restrict__ ex,
    float* __restrict__ out)
{
  __shared__ __align__(16) unsigned short As[2 * RS];
  __shared__ float red[2][4][16][2];
  __shared__ int g;

  if (threadIdx.x == 0)
    g = (int)__hip_atomic_load(&((u32*)(ex + 8192))[2], __ATOMIC_RELAXED, __HIP_MEMORY_SCOPE_AGENT);
  __syncthreads();
  if (g == 1) return;              // wide kernel already produced the output

  const int tid = threadIdx.x;
  const int blk = blockIdx.x;      // 0..127
  const int r0  = (blk >> 5) << 1;
  const int cb  = blk & 31;
  const int wv  = tid >> 6;
  const int l   = tid & 63;
  const int m16 = l & 15;
  const int q   = l >> 4;
  const int cg  = wv >> 1;
  const int ks  = wv & 1;
  const int gcg = (cb << 2) + cg;
  const int colw0 = gcg << 4;

  short8 Bf[34];
  {
    const short8* bp = (const short8*)Bsw + (size_t)((gcg << 1) + ks) * 34 * 64 + l;
    #pragma unroll
    for (int f = 0; f < 34; ++f) Bf[f] = bp[f * 64];
  }
  const float bias = b_in[colw0 + m16];
  float s0 = 0.f, s1 = 0.f;

  const float* xr0 = inputs + (size_t)r0 * 1024 * 128;
  const u64 M = 0x0001000100010001ULL;

  for (int t = 0; t < 1024; ++t){
    if (tid < 64){
      const int row = tid >> 5;
      const int c   = tid & 31;
      float4 xv = ((const float4*)(xr0 + ((size_t)row * 1024 + t) * 128))[c];
      u64 pk = (u64)f2bf(xv.x) | ((u64)f2bf(xv.y) << 16)
             | ((u64)f2bf(xv.z) << 32) | ((u64)f2bf(xv.w) << 48);
      *((u64*)&As[row * RS + 2048 + (c << 2)]) = pk;
    }
    {
      u64* srcb = ex + ((size_t)(t & 1) * 8 + r0) * 512;
      const u64 wantm = ((t >> 1) & 1) ? M : 0ULL;
      u64 v0 = __hip_atomic_load(&srcb[tid],       __ATOMIC_RELAXED, __HIP_MEMORY_SCOPE_AGENT);
      u64 v1 = __hip_atomic_load(&srcb[512 + tid], __ATOMIC_RELAXED, __HIP_MEMORY_SCOPE_AGENT);
      u32 pend = 3;
      while (pend){
        u32 np = 0;
        if (pend & 1){
          if ((v0 & M) == wantm) *((u64*)&As[tid << 2]) = v0;
          else np |= 1;
        }
        if (pend & 2){
          if ((v1 & M) == wantm) *((u64*)&As[RS + (tid << 2)]) = v1;
          else np |= 2;
        }
        pend = np;
        if (pend & 1) v0 = __hip_atomic_load(&srcb[tid],       __ATOMIC_RELAXED, __HIP_MEMORY_SCOPE_AGENT);
        if (pend & 2) v1 = __hip_atomic_load(&srcb[512 + tid], __ATOMIC_RELAXED, __HIP_MEMORY_SCOPE_AGENT);
      }
    }
    __syncthreads();

    f32x4 acc0 = {0.f,0.f,0.f,0.f}, acc1 = {0.f,0.f,0.f,0.f};
    {
      const unsigned short* Ab = &As[(m16 & 1) * RS + ks * 1088 + (q << 3)];
      #pragma unroll
      for (int f = 0; f < 34; f += 2){
        short8 a0 = *((const short8*)(Ab + (f << 5)));
        short8 a1 = *((const short8*)(Ab + ((f + 1) << 5)));
        acc0 = __builtin_amdgcn_mfma_f32_16x16x32_bf16(a0, Bf[f],     acc0, 0, 0, 0);
        acc1 = __builtin_amdgcn_mfma_f32_16x16x32_bf16(a1, Bf[f + 1], acc1, 0, 0, 0);
      }
    }
    float p0 = acc0[0] + acc1[0];
    float p1 = acc0[1] + acc1[1];
    if (ks == 1 && l < 16){
      red[t & 1][cg][m16][0] = p0;
      red[t & 1][cg][m16][1] = p1;
    }
    __syncthreads();

    if (ks == 0 && l < 16){
      p0 += red[t & 1][cg][m16][0];
      p1 += red[t & 1][cg][m16][1];
      float nv0 = 0.5f * s0 + 0.5f * tanh_fast(p0 + bias);
      float nv1 = 0.5f * s1 + 0.5f * tanh_fast(p1 + bias);
      s0 = nv0; s1 = nv1;
      const u32 bit = (u32)(((t + 1) >> 1) & 1);
      u32 b0 = ((u32)f2bf(nv0) & 0xFFFEu) | bit;
      u32 b1 = ((u32)f2bf(nv1) & 0xFFFEu) | bit;
      u32 pr0 = b0 | (((u32)__shfl_xor((int)b0, 1)) << 16);
      u32 pr1 = b1 | (((u32)__shfl_xor((int)b1, 1)) << 16);
      u64 e0 = (u64)pr0 | ((u64)(u32)__shfl_xor((int)pr0, 2) << 32);
      u64 e1 = (u64)pr1 | ((u64)(u32)__shfl_xor((int)pr1, 2) << 32);
      const int u = colw0 + m16;
      if ((m16 & 3) == 0){
        u64* exw = ex + ((size_t)((t + 1) & 1) * 8 + r0) * 512;
        const int p = (colw0 + m16) >> 2;
        __hip_atomic_store(&exw[p],       e0, __ATOMIC_RELAXED, __HIP_MEMORY_SCOPE_AGENT);
        __hip_atomic_store(&exw[512 + p], e1, __ATOMIC_RELAXED, __HIP_MEMORY_SCOPE_AGENT);
      }
      float pw0 = (u & 1) ? nv0 : nv0 * nv0;
      float pw1 = (u & 1) ? nv1 : nv1 * nv1;
      out[((size_t)r0 * 1024 + t) * 2176 + 128 + u] = pw0;
      out[((size_t)(r0 + 1) * 1024 + t) * 2176 + 128 + u] = pw1;
    }
  }
}

extern "C" void kernel_launch(void* const* d_in, const int* in_sizes, int n_in,
                              void* d_out, int out_size, void* d_ws, size_t ws_size,
                              hipStream_t stream){
  const float* inputs = (const float*)d_in[0];   // [8,1024,128]
  const float* w_in   = (const float*)d_in[1];   // [128,2048]
  const float* b_in   = (const float*)d_in[2];   // [2048]
  const float* w_res  = (const float*)d_in[3];   // [2048,2048]
  float* out = (float*)d_out;

  u64* ex = (u64*)d_ws;                                         // 8704 u64 = 69632 B
  unsigned short* Bsw = (unsigned short*)((char*)d_ws + 69632); // 8,912,896 B swizzled weights

  exinit_kernel<<<34, 256, 0, stream>>>(ex);
  bswz_kernel<<<2176, 256, 0, stream>>>(w_res, w_in, Bsw);
  copy_in_kernel<<<1024, 256, 0, stream>>>(inputs, out);
  esn_wide<<<256, 256, 0, stream>>>(inputs, b_in, Bsw, ex, out);
  esn_safe<<<128, 512, 0, stream>>>(inputs, b_in, Bsw, ex, out);
}

// Round 3
// 5197.660 us; speedup vs baseline: 1.3775x; 1.3775x over previous
//
#include <hip/hip_runtime.h>
#include <cmath>

typedef __attribute__((ext_vector_type(8))) short short8;
typedef __attribute__((ext_vector_type(4))) float f32x4;
typedef __attribute__((ext_vector_type(4))) unsigned int u32x4;
typedef unsigned long long u64;
typedef unsigned int u32;

#define RS 2208             // safe-kernel A row stride in bf16
#define TICKS_MS 100000ull  // s_memrealtime ~100 MHz -> 1 ms
#define SCAN_SPIN (1u << 18)
#define AG __ATOMIC_RELAXED, __HIP_MEMORY_SCOPE_AGENT

__device__ __forceinline__ unsigned short f2bf(float x){
  u32 u = __float_as_uint(x);
  u32 r = u + 0x7FFFu + ((u >> 16) & 1u);   // round-to-nearest-even bf16
  return (unsigned short)(r >> 16);
}

__device__ __forceinline__ float tanh_fast(float x){
  float xc = fminf(fmaxf(x, -10.f), 10.f);
  float e = __expf(2.f * xc);
  return (e - 1.f) / (e + 1.f);
}

__device__ __forceinline__ u64 rtc(){ return __builtin_amdgcn_s_memrealtime(); }

// sc0 (SE-scope) ops: bypass L1, meet in the XCD-shared L2. Used ONLY between
// blocks PROVEN co-XCD by HW_REG_XCC_ID self-assignment AND a bounded lockstep
// ping-pong that verifies value-change visibility.
__device__ __forceinline__ u64 ld8_sc0(const u64* p){
  u64 v;
  asm volatile("global_load_dwordx2 %0, %1, off sc0\n\ts_waitcnt vmcnt(0)"
               : "=v"(v) : "v"(p) : "memory");
  return v;
}
__device__ __forceinline__ void st8_sc0(u64* p, u64 v){
  asm volatile("global_store_dwordx2 %0, %1, off sc0" :: "v"(p), "v"(v) : "memory");
}
__device__ __forceinline__ u32x4 ld16_sc0(const u64* p){
  u32x4 v;
  asm volatile("global_load_dwordx4 %0, %1, off sc0\n\ts_waitcnt vmcnt(0)"
               : "=v"(v) : "v"(p) : "memory");
  return v;
}

// Pre-swizzle [w_res ; w_in] (K=2176 x 2048 cols) into bf16 MFMA B-fragment order.
// short8 index = ((gcg*68 + fu)*64 + l); k = fu*32 + (l>>4)*8 + j, col = gcg*16 + (l&15).
__global__ void bswz_kernel(const float* __restrict__ wres,
                            const float* __restrict__ win,
                            unsigned short* __restrict__ B){
  int tid = blockIdx.x * 256 + threadIdx.x;
  int l   = tid & 63;
  int cf  = tid >> 6;
  int f   = cf % 34;
  int gk  = cf / 34;
  int ks  = gk & 1;
  int gcg = gk >> 1;
  int col = (gcg << 4) + (l & 15);
  int k0  = ks * 1088 + (f << 5) + ((l >> 4) << 3);
  short8 vv;
  #pragma unroll
  for (int j = 0; j < 8; ++j){
    int k = k0 + j;
    float v = (k < 2048) ? wres[(size_t)k * 2048 + col]
                         : win[(size_t)(k - 2048) * 2048 + col];
    vv[j] = (short)f2bf(v);
  }
  *((short8*)(B + (size_t)tid * 8)) = vv;
}

// out[b][t][0:128] = inputs  (concat head).
__global__ void copy_in_kernel(const float* __restrict__ in, float* __restrict__ out){
  int i = blockIdx.x * 256 + threadIdx.x;
  int bt = i >> 5;
  int d4 = i & 31;
  float4 v = ((const float4*)in)[i];
  ((float4*)(out + (size_t)bt * 2176))[d4] = v;
}

// ex[2][8][512] u64 tagged state exchange, then ctrl u32[16]
// ([0]=ticket [1]=ok [2]=badA [3]=badP [4]=verdict [8..15]=per-XCD rank counters)
// then tslots[256] u64. All control state zeroed every launch.
__global__ void exinit_kernel(u64* __restrict__ ex){
  int i = blockIdx.x * 256 + threadIdx.x;   // 8704 entries
  if (i < 8192)      ex[i] = (i < 4096) ? 0ULL : 0x0001000100010001ULL;
  else if (i < 8704) ex[i] = 0ULL;
}

// ---------------- WIDE: 256 blocks x 256 threads, 1 block/CU ----------------
// Self-organized: block reads its XCD id (HW_REG_XCC_ID), claims rank within
// that XCD -> (r=xcd, cb=rank). With 1 block/CU and 32 CUs/XCD every XCD hosts
// exactly 32 blocks, so each row-ring is XCD-local BY CONSTRUCTION (no mapping
// assumption). Bounded sc0 ping-pong then tests ONLY sc0 semantics.
// verdict 1: sc0 exchange; 2: agent-scope exchange (same structure); 3: exit.
__global__ void __launch_bounds__(256, 1) esn_wide(
    const float* __restrict__ inputs,
    const float* __restrict__ b_in,
    const unsigned short* __restrict__ Bsw,
    u64* __restrict__ ex,
    float* __restrict__ out)
{
  __shared__ __align__(16) unsigned short As[2][2176]; // [parity][2048 state + 128 x_t]
  __shared__ int s_r, s_cb, s_mode;

  const int tid = threadIdx.x;
  u32* ctrl   = (u32*)(ex + 8192);
  u64* tslots = ex + 8192 + 8;

  // ---- clock-bounded pre-flight (tid 0; leader = ticket 0, always exists) ----
  if (tid == 0){
    u32 x  = __builtin_amdgcn_s_getreg(6164);   // hwreg(HW_REG_XCC_ID=20, off 0, sz 4)
    u32 tk = __hip_atomic_fetch_add(&ctrl[0], 1u, AG);
    u32 rank = __hip_atomic_fetch_add(&ctrl[8 + (x & 7u)], 1u, AG);
    int okA = (x < 8u) && (rank < 32u);
    s_r  = (int)(x & 7u);
    s_cb = (int)(rank & 31u);
    if (!okA){
      __hip_atomic_fetch_add(&ctrl[2], 1u, AG);             // badA: assignment invalid
    } else {
      u64* my = &tslots[(x << 5) | rank];
      u64* pa = &tslots[(x << 5) | ((rank + 1u) & 31u)];    // ring neighbor, same XCD
      int ok = 1;
      for (u64 rd = 1; rd <= 4 && ok; ++rd){                // lockstep: needs FRESH values
        st8_sc0(my, rd);
        u64 tend = rtc() + TICKS_MS;
        u64 v;
        do { v = ld8_sc0(pa); } while (v < rd && rtc() < tend);
        ok = (v >= rd) ? 1 : 0;
      }
      __hip_atomic_fetch_add(&ctrl[ok ? 1 : 3], 1u, AG);    // ok / badP
    }
    if (tk == 0u){                                          // leader decides once
      u64 tend = rtc() + 3 * TICKS_MS;
      u32 a, bA, bP;
      do {
        a  = __hip_atomic_load(&ctrl[1], AG);
        bA = __hip_atomic_load(&ctrl[2], AG);
        bP = __hip_atomic_load(&ctrl[3], AG);
      } while (a + bA + bP < 256u && rtc() < tend);
      u32 v = (a == 256u) ? 1u : ((bA == 0u && a + bA + bP == 256u) ? 2u : 3u);
      __hip_atomic_store(&ctrl[4], v, AG);
    }
    u64 tend = rtc() + 50 * TICKS_MS;
    u32 v;
    do { v = __hip_atomic_load(&ctrl[4], AG); } while (v == 0u && rtc() < tend);
    s_mode = (v == 1u) ? 1 : ((v == 2u) ? 0 : -1);
  }
  __syncthreads();
  const int mode = s_mode;
  if (mode < 0) return;            // esn_safe takes over (verdict 3)
  const bool fast = (mode == 1);
  const int r  = s_r;
  const int cb = s_cb;

  // ---- committed: B fragments for full K=2176 (68 short8; unified VGPR/AGPR) ----
  const int w   = tid >> 6;        // wave 0..3 = col-group
  const int l   = tid & 63;
  const int m16 = l & 15;
  const int q   = l >> 4;
  const int gcg = (cb << 2) + w;   // 0..127
  const int colw0 = gcg << 4;

  short8 Bf[68];
  {
    const short8* bp = (const short8*)Bsw + (size_t)gcg * (68 * 64) + l;
    #pragma unroll
    for (int f = 0; f < 68; ++f) Bf[f] = bp[f * 64];
  }
  const float bias = b_in[colw0 + m16];
  float s = 0.f;
  const float* xr = inputs + (size_t)r * 1024 * 128;
  const u64 M = 0x0001000100010001ULL;

  float4 xv;
  if (tid < 32) xv = ((const float4*)xr)[tid];      // prefetch x_0

  for (int t = 0; t < 1024; ++t){
    const int p = t & 1;
    unsigned short* Ap = &As[p][0];

    // stage x_t from regs; issue prefetch of x_{t+1} (overlaps the poll)
    if (tid < 32){
      u64 pk = (u64)f2bf(xv.x) | ((u64)f2bf(xv.y) << 16)
             | ((u64)f2bf(xv.z) << 32) | ((u64)f2bf(xv.w) << 48);
      *((u64*)&Ap[2048 + (tid << 2)]) = pk;
      if (t < 1023) xv = ((const float4*)(xr + (size_t)(t + 1) * 128))[tid];
    }
    // poll: ONE 16B load per thread covers both of its entries (single wait)
    {
      u64* srcb = ex + ((size_t)p * 8 + r) * 512;
      const u64 want = ((t >> 1) & 1) ? M : 0ULL;
      const u64* myp = &srcb[tid << 1];
      u64 v01, v23;
      if (fast){
        u32x4 v = ld16_sc0(myp);
        v01 = (u64)v.x | ((u64)v.y << 32);
        v23 = (u64)v.z | ((u64)v.w << 32);
      } else {
        v01 = __hip_atomic_load(&srcb[tid << 1],       AG);
        v23 = __hip_atomic_load(&srcb[(tid << 1) + 1], AG);
      }
      u32 guard = 0;
      while (((v01 & M) != want) || ((v23 & M) != want)){
        if (++guard > SCAN_SPIN) break;     // liveness guard: never hang
        if (fast){
          u32x4 v = ld16_sc0(myp);
          v01 = (u64)v.x | ((u64)v.y << 32);
          v23 = (u64)v.z | ((u64)v.w << 32);
        } else {
          v01 = __hip_atomic_load(&srcb[tid << 1],       AG);
          v23 = __hip_atomic_load(&srcb[(tid << 1) + 1], AG);
        }
      }
      *((u64*)&Ap[(tid << 3)])     = v01;   // contiguous 16B at Ap + tid*16
      *((u64*)&Ap[(tid << 3) + 4]) = v23;
    }
    __syncthreads();   // single barrier/step; As parity-double-buffered

    // MFMA: full K=2176, 68 x 16x16x32, 4 interleaved acc chains, M=1 broadcast
    f32x4 a0 = {0,0,0,0}, a1 = {0,0,0,0}, a2 = {0,0,0,0}, a3 = {0,0,0,0};
    {
      const unsigned short* Ab = Ap + (q << 3);
      #pragma unroll
      for (int f = 0; f < 68; f += 4){
        short8 x0 = *((const short8*)(Ab + ((f + 0) << 5)));
        short8 x1 = *((const short8*)(Ab + ((f + 1) << 5)));
        short8 x2 = *((const short8*)(Ab + ((f + 2) << 5)));
        short8 x3 = *((const short8*)(Ab + ((f + 3) << 5)));
        a0 = __builtin_amdgcn_mfma_f32_16x16x32_bf16(x0, Bf[f + 0], a0, 0, 0, 0);
        a1 = __builtin_amdgcn_mfma_f32_16x16x32_bf16(x1, Bf[f + 1], a1, 0, 0, 0);
        a2 = __builtin_amdgcn_mfma_f32_16x16x32_bf16(x2, Bf[f + 2], a2, 0, 0, 0);
        a3 = __builtin_amdgcn_mfma_f32_16x16x32_bf16(x3, Bf[f + 3], a3, 0, 0, 0);
      }
    }
    if (l < 16){
      float pre = ((a0[0] + a1[0]) + (a2[0] + a3[0])) + bias;
      float nv = 0.5f * s + 0.5f * tanh_fast(pre);
      s = nv;
      const u32 bit = (u32)(((t + 1) >> 1) & 1);
      u32 b0 = ((u32)f2bf(nv) & 0xFFFEu) | bit;        // tag-bit in bf16 LSB
      u32 pr = b0 | (((u32)__shfl_xor((int)b0, 1)) << 16);
      u64 e  = (u64)pr | ((u64)(u32)__shfl_xor((int)pr, 2) << 32);
      if ((m16 & 3) == 0){
        u64* exw = ex + ((size_t)((t + 1) & 1) * 8 + r) * 512;
        u64* dst = &exw[(colw0 + m16) >> 2];
        if (fast) st8_sc0(dst, e);                     // publish first
        else __hip_atomic_store(dst, e, AG);
      }
      const int u = colw0 + m16;
      float pw = (u & 1) ? nv : nv * nv;               // PowerIndex: even u squared
      out[((size_t)r * 1024 + t) * 2176 + 128 + u] = pw;
    }
  }
}

// ---------------- SAFE: verbatim proven 3.08ms kernel, verdict-gated ----------------
__global__ void __launch_bounds__(512, 2) esn_safe(
    const float* __restrict__ inputs,
    const float* __restrict__ b_in,
    const unsigned short* __restrict__ Bsw,
    u64* __restrict__ ex,
    float* __restrict__ out)
{
  __shared__ __align__(16) unsigned short As[2 * RS];
  __shared__ float red[2][4][16][2];
  __shared__ int g;

  if (threadIdx.x == 0)
    g = (int)__hip_atomic_load(&((u32*)(ex + 8192))[4], AG);
  __syncthreads();
  if (g != 3) return;              // wide kernel already produced the output

  const int tid = threadIdx.x;
  const int blk = blockIdx.x;      // 0..127
  const int r0  = (blk >> 5) << 1;
  const int cb  = blk & 31;
  const int wv  = tid >> 6;
  const int l   = tid & 63;
  const int m16 = l & 15;
  const int q   = l >> 4;
  const int cg  = wv >> 1;
  const int ks  = wv & 1;
  const int gcg = (cb << 2) + cg;
  const int colw0 = gcg << 4;

  short8 Bf[34];
  {
    const short8* bp = (const short8*)Bsw + (size_t)((gcg << 1) + ks) * 34 * 64 + l;
    #pragma unroll
    for (int f = 0; f < 34; ++f) Bf[f] = bp[f * 64];
  }
  const float bias = b_in[colw0 + m16];
  float s0 = 0.f, s1 = 0.f;

  const float* xr0 = inputs + (size_t)r0 * 1024 * 128;
  const u64 M = 0x0001000100010001ULL;

  for (int t = 0; t < 1024; ++t){
    if (tid < 64){
      const int row = tid >> 5;
      const int c   = tid & 31;
      float4 xv = ((const float4*)(xr0 + ((size_t)row * 1024 + t) * 128))[c];
      u64 pk = (u64)f2bf(xv.x) | ((u64)f2bf(xv.y) << 16)
             | ((u64)f2bf(xv.z) << 32) | ((u64)f2bf(xv.w) << 48);
      *((u64*)&As[row * RS + 2048 + (c << 2)]) = pk;
    }
    {
      u64* srcb = ex + ((size_t)(t & 1) * 8 + r0) * 512;
      const u64 wantm = ((t >> 1) & 1) ? M : 0ULL;
      u64 v0 = __hip_atomic_load(&srcb[tid],       AG);
      u64 v1 = __hip_atomic_load(&srcb[512 + tid], AG);
      u32 pend = 3;
      while (pend){
        u32 np = 0;
        if (pend & 1){
          if ((v0 & M) == wantm) *((u64*)&As[tid << 2]) = v0;
          else np |= 1;
        }
        if (pend & 2){
          if ((v1 & M) == wantm) *((u64*)&As[RS + (tid << 2)]) = v1;
          else np |= 2;
        }
        pend = np;
        if (pend & 1) v0 = __hip_atomic_load(&srcb[tid],       AG);
        if (pend & 2) v1 = __hip_atomic_load(&srcb[512 + tid], AG);
      }
    }
    __syncthreads();

    f32x4 acc0 = {0.f,0.f,0.f,0.f}, acc1 = {0.f,0.f,0.f,0.f};
    {
      const unsigned short* Ab = &As[(m16 & 1) * RS + ks * 1088 + (q << 3)];
      #pragma unroll
      for (int f = 0; f < 34; f += 2){
        short8 a0 = *((const short8*)(Ab + (f << 5)));
        short8 a1 = *((const short8*)(Ab + ((f + 1) << 5)));
        acc0 = __builtin_amdgcn_mfma_f32_16x16x32_bf16(a0, Bf[f],     acc0, 0, 0, 0);
        acc1 = __builtin_amdgcn_mfma_f32_16x16x32_bf16(a1, Bf[f + 1], acc1, 0, 0, 0);
      }
    }
    float p0 = acc0[0] + acc1[0];
    float p1 = acc0[1] + acc1[1];
    if (ks == 1 && l < 16){
      red[t & 1][cg][m16][0] = p0;
      red[t & 1][cg][m16][1] = p1;
    }
    __syncthreads();

    if (ks == 0 && l < 16){
      p0 += red[t & 1][cg][m16][0];
      p1 += red[t & 1][cg][m16][1];
      float nv0 = 0.5f * s0 + 0.5f * tanh_fast(p0 + bias);
      float nv1 = 0.5f * s1 + 0.5f * tanh_fast(p1 + bias);
      s0 = nv0; s1 = nv1;
      const u32 bit = (u32)(((t + 1) >> 1) & 1);
      u32 b0 = ((u32)f2bf(nv0) & 0xFFFEu) | bit;
      u32 b1 = ((u32)f2bf(nv1) & 0xFFFEu) | bit;
      u32 pr0 = b0 | (((u32)__shfl_xor((int)b0, 1)) << 16);
      u32 pr1 = b1 | (((u32)__shfl_xor((int)b1, 1)) << 16);
      u64 e0 = (u64)pr0 | ((u64)(u32)__shfl_xor((int)pr0, 2) << 32);
      u64 e1 = (u64)pr1 | ((u64)(u32)__shfl_xor((int)pr1, 2) << 32);
      const int u = colw0 + m16;
      if ((m16 & 3) == 0){
        u64* exw = ex + ((size_t)((t + 1) & 1) * 8 + r0) * 512;
        const int p = (colw0 + m16) >> 2;
        __hip_atomic_store(&exw[p],       e0, AG);
        __hip_atomic_store(&exw[512 + p], e1, AG);
      }
      float pw0 = (u & 1) ? nv0 : nv0 * nv0;
      float pw1 = (u & 1) ? nv1 : nv1 * nv1;
      out[((size_t)r0 * 1024 + t) * 2176 + 128 + u] = pw0;
      out[((size_t)(r0 + 1) * 1024 + t) * 2176 + 128 + u] = pw1;
    }
  }
}

extern "C" void kernel_launch(void* const* d_in, const int* in_sizes, int n_in,
                              void* d_out, int out_size, void* d_ws, size_t ws_size,
                              hipStream_t stream){
  const float* inputs = (const float*)d_in[0];   // [8,1024,128]
  const float* w_in   = (const float*)d_in[1];   // [128,2048]
  const float* b_in   = (const float*)d_in[2];   // [2048]
  const float* w_res  = (const float*)d_in[3];   // [2048,2048]
  float* out = (float*)d_out;

  u64* ex = (u64*)d_ws;                                         // 8704 u64 = 69632 B
  unsigned short* Bsw = (unsigned short*)((char*)d_ws + 69632); // 8,912,896 B swizzled weights

  exinit_kernel<<<34, 256, 0, stream>>>(ex);
  bswz_kernel<<<2176, 256, 0, stream>>>(w_res, w_in, Bsw);
  copy_in_kernel<<<1024, 256, 0, stream>>>(inputs, out);
  esn_wide<<<256, 256, 0, stream>>>(inputs, b_in, Bsw, ex, out);
  esn_safe<<<128, 512, 0, stream>>>(inputs, b_in, Bsw, ex, out);
}

// Round 4
// 4975.669 us; speedup vs baseline: 1.4389x; 1.0446x over previous
//
#include <hip/hip_runtime.h>
#include <cmath>

typedef __attribute__((ext_vector_type(8))) short short8;
typedef __attribute__((ext_vector_type(4))) float f32x4;
typedef __attribute__((ext_vector_type(4))) unsigned int u32x4;
typedef unsigned long long u64;
typedef unsigned int u32;

#define RS 2208             // safe-kernel A row stride in bf16
#define TICKS_MS 100000ull  // s_memrealtime ~100 MHz -> 1 ms
#define SCAN_SPIN (1u << 18)
#define AG __ATOMIC_RELAXED, __HIP_MEMORY_SCOPE_AGENT

__device__ __forceinline__ unsigned short f2bf(float x){
  u32 u = __float_as_uint(x);
  u32 r = u + 0x7FFFu + ((u >> 16) & 1u);   // round-to-nearest-even bf16
  return (unsigned short)(r >> 16);
}

__device__ __forceinline__ float tanh_fast(float x){
  float xc = fminf(fmaxf(x, -10.f), 10.f);
  float e = __expf(2.f * xc);
  return (e - 1.f) / (e + 1.f);
}

__device__ __forceinline__ u64 rtc(){ return __builtin_amdgcn_s_memrealtime(); }

// sc0 (SE-scope) ops: bypass L1, meet in the XCD-shared L2. Proven functional in
// r3 (FETCH_SIZE showed polls were L2-local). Used only between blocks proven
// co-XCD by HW_REG_XCC_ID self-assignment + bounded lockstep ping-pong.
__device__ __forceinline__ u64 ld8_sc0(const u64* p){
  u64 v;
  asm volatile("global_load_dwordx2 %0, %1, off sc0\n\ts_waitcnt vmcnt(0)"
               : "=v"(v) : "v"(p) : "memory");
  return v;
}
__device__ __forceinline__ void st8_sc0(u64* p, u64 v){
  asm volatile("global_store_dwordx2 %0, %1, off sc0" :: "v"(p), "v"(v) : "memory");
}
__device__ __forceinline__ u32x4 ld16_sc0(const u64* p){
  u32x4 v;
  asm volatile("global_load_dwordx4 %0, %1, off sc0\n\ts_waitcnt vmcnt(0)"
               : "=v"(v) : "v"(p) : "memory");
  return v;
}

// Pre-swizzle [w_res ; w_in] (K=2176 x 2048 cols) into bf16 MFMA B-fragment order.
// short8 index = ((gcg*68 + fu)*64 + l); k = fu*32 + (l>>4)*8 + j, col = gcg*16 + (l&15).
__global__ void bswz_kernel(const float* __restrict__ wres,
                            const float* __restrict__ win,
                            unsigned short* __restrict__ B){
  int tid = blockIdx.x * 256 + threadIdx.x;
  int l   = tid & 63;
  int cf  = tid >> 6;
  int f   = cf % 34;
  int gk  = cf / 34;
  int ks  = gk & 1;
  int gcg = gk >> 1;
  int col = (gcg << 4) + (l & 15);
  int k0  = ks * 1088 + (f << 5) + ((l >> 4) << 3);
  short8 vv;
  #pragma unroll
  for (int j = 0; j < 8; ++j){
    int k = k0 + j;
    float v = (k < 2048) ? wres[(size_t)k * 2048 + col]
                         : win[(size_t)(k - 2048) * 2048 + col];
    vv[j] = (short)f2bf(v);
  }
  *((short8*)(B + (size_t)tid * 8)) = vv;
}

// out[b][t][0:128] = inputs  (concat head).
__global__ void copy_in_kernel(const float* __restrict__ in, float* __restrict__ out){
  int i = blockIdx.x * 256 + threadIdx.x;
  int bt = i >> 5;
  int d4 = i & 31;
  float4 v = ((const float4*)in)[i];
  ((float4*)(out + (size_t)bt * 2176))[d4] = v;
}

// ex[2][8][512] u64 tagged exchange; ctrl u32[16] at ex[8192]
// ([0]=ticket [1]=ok [2]=badA [3]=badP [4]=verdict [8..15]=per-XCD rank ctr);
// tslots[512] u64 at ex[8200]. Zeroed every launch.
__global__ void exinit_kernel(u64* __restrict__ ex){
  int i = blockIdx.x * 256 + threadIdx.x;   // 35*256 = 8960 entries
  if (i < 8192)      ex[i] = (i < 4096) ? 0ULL : 0x0001000100010001ULL;
  else if (i < 8960) ex[i] = 0ULL;
}

// ---------------- WIDE: 512 blocks x 256 threads, 2 blocks/CU ----------------
// Self-organized: block reads HW_REG_XCC_ID, claims rank 0..63 within its XCD
// -> (row = xcd, cols [rank*32, rank*32+32)). Grid == residency capacity, so
// each XCD hosts exactly 64 blocks; every row-ring is XCD-local by construction.
// Waves: 2 col-groups x 2 K-halves (34 frags/wave) + LDS ks-reduce => 2 waves/SIMD
// for latency hiding (r3 ran 1 wave/SIMD and serialized the whole step).
// verdict 1: sc0 exchange; 2: agent-scope, same structure; 3: exit -> esn_safe.
__global__ void __launch_bounds__(256, 2) esn_wide(
    const float* __restrict__ inputs,
    const float* __restrict__ b_in,
    const unsigned short* __restrict__ Bsw,
    u64* __restrict__ ex,
    float* __restrict__ out)
{
  __shared__ __align__(16) unsigned short As[2][2176]; // [parity][2048 state + 128 x_t]
  __shared__ float red[2][2][16];                      // [parity][cg][m16]
  __shared__ int s_r, s_cb, s_mode;

  const int tid = threadIdx.x;
  u32* ctrl   = (u32*)(ex + 8192);
  u64* tslots = ex + 8192 + 8;

  // ---- clock-bounded pre-flight (tid 0; leader = ticket 0, always exists) ----
  if (tid == 0){
    u32 x  = __builtin_amdgcn_s_getreg(6164);   // hwreg(HW_REG_XCC_ID=20, 0, 4)
    u32 tk = __hip_atomic_fetch_add(&ctrl[0], 1u, AG);
    u32 rank = __hip_atomic_fetch_add(&ctrl[8 + (x & 7u)], 1u, AG);
    int okA = (x < 8u) && (rank < 64u);
    s_r  = (int)(x & 7u);
    s_cb = (int)(rank & 63u);
    if (!okA){
      __hip_atomic_fetch_add(&ctrl[2], 1u, AG);             // badA
    } else {
      u64* my = &tslots[(x << 6) | rank];
      u64* pa = &tslots[(x << 6) | ((rank + 1u) & 63u)];    // ring neighbor, same XCD
      int ok = 1;
      for (u64 rd = 1; rd <= 4 && ok; ++rd){                // lockstep: needs FRESH values
        st8_sc0(my, rd);
        u64 tend = rtc() + TICKS_MS;
        u64 v;
        do { v = ld8_sc0(pa); } while (v < rd && rtc() < tend);
        ok = (v >= rd) ? 1 : 0;
      }
      __hip_atomic_fetch_add(&ctrl[ok ? 1 : 3], 1u, AG);    // ok / badP
    }
    if (tk == 0u){                                          // leader decides once
      u64 tend = rtc() + 3 * TICKS_MS;
      u32 a, bA, bP;
      do {
        a  = __hip_atomic_load(&ctrl[1], AG);
        bA = __hip_atomic_load(&ctrl[2], AG);
        bP = __hip_atomic_load(&ctrl[3], AG);
      } while (a + bA + bP < 512u && rtc() < tend);
      u32 v = (a == 512u) ? 1u : ((bA == 0u && a + bA + bP == 512u) ? 2u : 3u);
      __hip_atomic_store(&ctrl[4], v, AG);
    }
    u64 tend = rtc() + 50 * TICKS_MS;
    u32 v;
    do { v = __hip_atomic_load(&ctrl[4], AG); } while (v == 0u && rtc() < tend);
    s_mode = (v == 1u) ? 1 : ((v == 2u) ? 0 : -1);
  }
  __syncthreads();
  const int mode = s_mode;
  if (mode < 0) return;            // esn_safe takes over (verdict 3)
  const bool fast = (mode == 1);
  const int r  = s_r;
  const int cb = s_cb;             // 0..63: cols [cb*32, cb*32+32)

  const int wv  = tid >> 6;        // 0..3
  const int l   = tid & 63;
  const int m16 = l & 15;
  const int q   = l >> 4;
  const int cg  = wv >> 1;         // col-group 0/1
  const int ks  = wv & 1;          // K-half 0/1
  const int gcg = (cb << 1) + cg;  // 0..127
  const int colw0 = gcg << 4;

  // B fragments: 34 short8 = 136 VGPR (fits 2 waves/SIMD at <=256)
  short8 Bf[34];
  {
    const short8* bp = (const short8*)Bsw + (size_t)(gcg * 68 + ks * 34) * 64 + l;
    #pragma unroll
    for (int f = 0; f < 34; ++f) Bf[f] = bp[f * 64];
  }
  const float bias = b_in[colw0 + m16];
  float s = 0.f;
  const float* xr = inputs + (size_t)r * 1024 * 128;
  const u64 M = 0x0001000100010001ULL;

  float4 xv;
  if (tid < 32) xv = ((const float4*)xr)[tid];      // prefetch x_0

  for (int t = 0; t < 1024; ++t){
    const int p = t & 1;
    unsigned short* Ap = &As[p][0];

    // stage x_t from regs; issue prefetch of x_{t+1} (overlaps the poll)
    if (tid < 32){
      u64 pk = (u64)f2bf(xv.x) | ((u64)f2bf(xv.y) << 16)
             | ((u64)f2bf(xv.z) << 32) | ((u64)f2bf(xv.w) << 48);
      *((u64*)&Ap[2048 + (tid << 2)]) = pk;
      if (t < 1023) xv = ((const float4*)(xr + (size_t)(t + 1) * 128))[tid];
    }
    // poll: ONE 16B load per thread covers both of its entries (single wait)
    {
      u64* srcb = ex + ((size_t)p * 8 + r) * 512;
      const u64 want = ((t >> 1) & 1) ? M : 0ULL;
      const u64* myp = &srcb[tid << 1];
      u64 v01, v23;
      if (fast){
        u32x4 v = ld16_sc0(myp);
        v01 = (u64)v.x | ((u64)v.y << 32);
        v23 = (u64)v.z | ((u64)v.w << 32);
      } else {
        v01 = __hip_atomic_load(&srcb[tid << 1],       AG);
        v23 = __hip_atomic_load(&srcb[(tid << 1) + 1], AG);
      }
      u32 guard = 0;
      while (((v01 & M) != want) || ((v23 & M) != want)){
        if (++guard > SCAN_SPIN) break;     // liveness guard: never hang
        if (fast){
          u32x4 v = ld16_sc0(myp);
          v01 = (u64)v.x | ((u64)v.y << 32);
          v23 = (u64)v.z | ((u64)v.w << 32);
        } else {
          v01 = __hip_atomic_load(&srcb[tid << 1],       AG);
          v23 = __hip_atomic_load(&srcb[(tid << 1) + 1], AG);
        }
      }
      *((u64*)&Ap[(tid << 3)])     = v01;   // contiguous 16B at Ap + tid*16
      *((u64*)&Ap[(tid << 3) + 4]) = v23;
    }
    __syncthreads();

    // MFMA: K-half per wave, 34 x 16x16x32, 2 interleaved acc chains.
    // A identical across lanes (broadcast) -> every D row valid; use reg 0.
    f32x4 a0 = {0,0,0,0}, a1 = {0,0,0,0};
    {
      const unsigned short* Ab = Ap + ks * 1088 + (q << 3);
      #pragma unroll
      for (int f = 0; f < 34; f += 2){
        short8 x0 = *((const short8*)(Ab + ((f + 0) << 5)));
        short8 x1 = *((const short8*)(Ab + ((f + 1) << 5)));
        a0 = __builtin_amdgcn_mfma_f32_16x16x32_bf16(x0, Bf[f + 0], a0, 0, 0, 0);
        a1 = __builtin_amdgcn_mfma_f32_16x16x32_bf16(x1, Bf[f + 1], a1, 0, 0, 0);
      }
    }
    float pp = a0[0] + a1[0];
    if (ks == 1 && l < 16) red[p][cg][m16] = pp;
    __syncthreads();

    if (ks == 0 && l < 16){
      float pre = pp + red[p][cg][m16] + bias;
      float nv = 0.5f * s + 0.5f * tanh_fast(pre);
      s = nv;
      // publish FIRST (comm is the critical path), then out store
      const u32 bit = (u32)(((t + 1) >> 1) & 1);
      u32 b0 = ((u32)f2bf(nv) & 0xFFFEu) | bit;        // tag-bit in bf16 LSB
      u32 pr = b0 | (((u32)__shfl_xor((int)b0, 1)) << 16);
      u64 e  = (u64)pr | ((u64)(u32)__shfl_xor((int)pr, 2) << 32);
      if ((m16 & 3) == 0){
        u64* exw = ex + ((size_t)((t + 1) & 1) * 8 + r) * 512;
        u64* dst = &exw[(colw0 + m16) >> 2];
        if (fast) st8_sc0(dst, e);
        else __hip_atomic_store(dst, e, AG);
      }
      const int u = colw0 + m16;
      float pw = (u & 1) ? nv : nv * nv;               // PowerIndex: even u squared
      out[((size_t)r * 1024 + t) * 2176 + 128 + u] = pw;
    }
  }
}

// ---------------- SAFE: verbatim proven 3.08ms kernel, verdict-gated ----------------
__global__ void __launch_bounds__(512, 2) esn_safe(
    const float* __restrict__ inputs,
    const float* __restrict__ b_in,
    const unsigned short* __restrict__ Bsw,
    u64* __restrict__ ex,
    float* __restrict__ out)
{
  __shared__ __align__(16) unsigned short As[2 * RS];
  __shared__ float red[2][4][16][2];
  __shared__ int g;

  if (threadIdx.x == 0)
    g = (int)__hip_atomic_load(&((u32*)(ex + 8192))[4], AG);
  __syncthreads();
  if (g == 1 || g == 2) return;    // wide kernel already produced the output

  const int tid = threadIdx.x;
  const int blk = blockIdx.x;      // 0..127
  const int r0  = (blk >> 5) << 1;
  const int cb  = blk & 31;
  const int wv  = tid >> 6;
  const int l   = tid & 63;
  const int m16 = l & 15;
  const int q   = l >> 4;
  const int cg  = wv >> 1;
  const int ks  = wv & 1;
  const int gcg = (cb << 2) + cg;
  const int colw0 = gcg << 4;

  short8 Bf[34];
  {
    const short8* bp = (const short8*)Bsw + (size_t)((gcg << 1) + ks) * 34 * 64 + l;
    #pragma unroll
    for (int f = 0; f < 34; ++f) Bf[f] = bp[f * 64];
  }
  const float bias = b_in[colw0 + m16];
  float s0 = 0.f, s1 = 0.f;

  const float* xr0 = inputs + (size_t)r0 * 1024 * 128;
  const u64 M = 0x0001000100010001ULL;

  for (int t = 0; t < 1024; ++t){
    if (tid < 64){
      const int row = tid >> 5;
      const int c   = tid & 31;
      float4 xv = ((const float4*)(xr0 + ((size_t)row * 1024 + t) * 128))[c];
      u64 pk = (u64)f2bf(xv.x) | ((u64)f2bf(xv.y) << 16)
             | ((u64)f2bf(xv.z) << 32) | ((u64)f2bf(xv.w) << 48);
      *((u64*)&As[row * RS + 2048 + (c << 2)]) = pk;
    }
    {
      u64* srcb = ex + ((size_t)(t & 1) * 8 + r0) * 512;
      const u64 wantm = ((t >> 1) & 1) ? M : 0ULL;
      u64 v0 = __hip_atomic_load(&srcb[tid],       AG);
      u64 v1 = __hip_atomic_load(&srcb[512 + tid], AG);
      u32 pend = 3;
      while (pend){
        u32 np = 0;
        if (pend & 1){
          if ((v0 & M) == wantm) *((u64*)&As[tid << 2]) = v0;
          else np |= 1;
        }
        if (pend & 2){
          if ((v1 & M) == wantm) *((u64*)&As[RS + (tid << 2)]) = v1;
          else np |= 2;
        }
        pend = np;
        if (pend & 1) v0 = __hip_atomic_load(&srcb[tid],       AG);
        if (pend & 2) v1 = __hip_atomic_load(&srcb[512 + tid], AG);
      }
    }
    __syncthreads();

    f32x4 acc0 = {0.f,0.f,0.f,0.f}, acc1 = {0.f,0.f,0.f,0.f};
    {
      const unsigned short* Ab = &As[(m16 & 1) * RS + ks * 1088 + (q << 3)];
      #pragma unroll
      for (int f = 0; f < 34; f += 2){
        short8 a0 = *((const short8*)(Ab + (f << 5)));
        short8 a1 = *((const short8*)(Ab + ((f + 1) << 5)));
        acc0 = __builtin_amdgcn_mfma_f32_16x16x32_bf16(a0, Bf[f],     acc0, 0, 0, 0);
        acc1 = __builtin_amdgcn_mfma_f32_16x16x32_bf16(a1, Bf[f + 1], acc1, 0, 0, 0);
      }
    }
    float p0 = acc0[0] + acc1[0];
    float p1 = acc0[1] + acc1[1];
    if (ks == 1 && l < 16){
      red[t & 1][cg][m16][0] = p0;
      red[t & 1][cg][m16][1] = p1;
    }
    __syncthreads();

    if (ks == 0 && l < 16){
      p0 += red[t & 1][cg][m16][0];
      p1 += red[t & 1][cg][m16][1];
      float nv0 = 0.5f * s0 + 0.5f * tanh_fast(p0 + bias);
      float nv1 = 0.5f * s1 + 0.5f * tanh_fast(p1 + bias);
      s0 = nv0; s1 = nv1;
      const u32 bit = (u32)(((t + 1) >> 1) & 1);
      u32 b0 = ((u32)f2bf(nv0) & 0xFFFEu) | bit;
      u32 b1 = ((u32)f2bf(nv1) & 0xFFFEu) | bit;
      u32 pr0 = b0 | (((u32)__shfl_xor((int)b0, 1)) << 16);
      u32 pr1 = b1 | (((u32)__shfl_xor((int)b1, 1)) << 16);
      u64 e0 = (u64)pr0 | ((u64)(u32)__shfl_xor((int)pr0, 2) << 32);
      u64 e1 = (u64)pr1 | ((u64)(u32)__shfl_xor((int)pr1, 2) << 32);
      const int u = colw0 + m16;
      if ((m16 & 3) == 0){
        u64* exw = ex + ((size_t)((t + 1) & 1) * 8 + r0) * 512;
        const int p = (colw0 + m16) >> 2;
        __hip_atomic_store(&exw[p],       e0, AG);
        __hip_atomic_store(&exw[512 + p], e1, AG);
      }
      float pw0 = (u & 1) ? nv0 : nv0 * nv0;
      float pw1 = (u & 1) ? nv1 : nv1 * nv1;
      out[((size_t)r0 * 1024 + t) * 2176 + 128 + u] = pw0;
      out[((size_t)(r0 + 1) * 1024 + t) * 2176 + 128 + u] = pw1;
    }
  }
}

extern "C" void kernel_launch(void* const* d_in, const int* in_sizes, int n_in,
                              void* d_out, int out_size, void* d_ws, size_t ws_size,
                              hipStream_t stream){
  const float* inputs = (const float*)d_in[0];   // [8,1024,128]
  const float* w_in   = (const float*)d_in[1];   // [128,2048]
  const float* b_in   = (const float*)d_in[2];   // [2048]
  const float* w_res  = (const float*)d_in[3];   // [2048,2048]
  float* out = (float*)d_out;

  u64* ex = (u64*)d_ws;                                         // 8960 u64 = 71680 B (ex+ctrl+tslots)
  unsigned short* Bsw = (unsigned short*)((char*)d_ws + 71680); // 8,912,896 B swizzled weights

  exinit_kernel<<<35, 256, 0, stream>>>(ex);
  bswz_kernel<<<2176, 256, 0, stream>>>(w_res, w_in, Bsw);
  copy_in_kernel<<<1024, 256, 0, stream>>>(inputs, out);
  esn_wide<<<512, 256, 0, stream>>>(inputs, b_in, Bsw, ex, out);
  esn_safe<<<128, 512, 0, stream>>>(inputs, b_in, Bsw, ex, out);
}